// Round 7
// baseline (892.303 us; speedup 1.0000x reference)
//
#include <hip/hip_runtime.h>

#define Bb 64
#define Nn 1024
#define Cc 558
#define CP1 559
#define CPAD 560
#define ITERS 20
#define NW 16                  /* waves per block */
#define BLOCK 1024

#if __has_builtin(__builtin_amdgcn_rcpf)
#define RCP(x) __builtin_amdgcn_rcpf(x)
#else
#define RCP(x) (1.0f / (x))
#endif

__device__ __forceinline__ float wave_sum(float v) {
#pragma unroll
    for (int off = 32; off > 0; off >>= 1) v += __shfl_xor(v, off, 64);
    return v;
}
__device__ __forceinline__ float wave_max(float v) {
#pragma unroll
    for (int off = 32; off > 0; off >>= 1) v = fmaxf(v, __shfl_xor(v, off, 64));
    return v;
}

// ---------------- fp8 e4m3 helpers (values >= 0, normal range; HW-validated R5/R6) ----
#if __has_builtin(__builtin_amdgcn_cvt_pk_fp8_f32) && __has_builtin(__builtin_amdgcn_cvt_pk_f32_fp8)
#define HW_FP8 1
typedef float v2f __attribute__((ext_vector_type(2)));
#endif

__device__ __forceinline__ unsigned enc1_sw(float v) {
    if (!(v > 0.f)) return 0u;
    unsigned u = __float_as_uint(v);
    unsigned t = u + 0x7FFFFu + ((u >> 20) & 1u);   // RNE to 3 mantissa bits
    int e = (int)(t >> 23) - 120;
    if (e < 1) return 0u;
    if (e > 15) return 0x7Eu;
    return ((unsigned)e << 3) | ((t >> 20) & 7u);
}
__device__ __forceinline__ float dec1_sw(unsigned b8) {
    return b8 ? __uint_as_float((((b8 >> 3) + 120u) << 23) | ((b8 & 7u) << 20)) : 0.f;
}
__device__ __forceinline__ unsigned enc4(float f0, float f1, float f2, float f3) {
#ifdef HW_FP8
    int w = 0;
    w = __builtin_amdgcn_cvt_pk_fp8_f32(f0, f1, w, false);
    w = __builtin_amdgcn_cvt_pk_fp8_f32(f2, f3, w, true);
    return (unsigned)w;
#else
    return enc1_sw(f0) | (enc1_sw(f1) << 8) | (enc1_sw(f2) << 16) | (enc1_sw(f3) << 24);
#endif
}
__device__ __forceinline__ void dec4(unsigned w, float& f0, float& f1, float& f2, float& f3) {
#ifdef HW_FP8
    v2f a = __builtin_amdgcn_cvt_pk_f32_fp8((int)w, false);
    v2f b = __builtin_amdgcn_cvt_pk_f32_fp8((int)w, true);
    f0 = a[0]; f1 = a[1]; f2 = b[0]; f3 = b[1];
#else
    f0 = dec1_sw(w & 0xffu); f1 = dec1_sw((w >> 8) & 0xffu);
    f2 = dec1_sw((w >> 16) & 0xffu); f3 = dec1_sw(w >> 24);
#endif
}
__device__ __forceinline__ float dec1(unsigned b8) {
#ifdef HW_FP8
    v2f a = __builtin_amdgcn_cvt_pk_f32_fp8((int)b8, false);
    return a[0];
#else
    return dec1_sw(b8);
#endif
}

// ============ K_FUSED: one block per batch; everything except the final mean ============
// Thread layout: 16 waves; wave w owns rows w*64..w*64+63. Within a row, lane l owns
// columns {64k+l, k=0..7} + tail column 512+l (l<46). q stored fp8 row-scaled in global:
// byte row*560 + 8*l + k  holds col 64k+l;  byte row*560 + 512 + l holds col 512+l.
__global__ __launch_bounds__(BLOCK) void k_fused(
        const float* __restrict__ logits, const float* __restrict__ dustbin,
        const int* __restrict__ labels, const void* __restrict__ maskp,
        unsigned char* __restrict__ p8, float* __restrict__ contrib) {
    __shared__ float partl[NW][CPAD];        // 35.8 KB
    __shared__ float evl[CPAD];
    __shared__ float lse_l[Nn];
    __shared__ float eu_l[Nn];
    __shared__ float qd_l[Nn];
    __shared__ unsigned char visc_l[Nn];
    __shared__ int cs_[Nn];
    __shared__ float redL[NW];
    __shared__ int sF, sB;
    __shared__ float sClass, sInvn;

    const int b = blockIdx.x, tid = threadIdx.x;
    const int wave = tid >> 6, lane = tid & 63;
    const bool tl = lane < 46;
    const float dustp = __expf(dustbin[0]);

    // ---------- A: mask format detect (first 4096 words are valid under any dtype) ----------
    if (tid == 0) { sF = 0; sB = 0; }
    __syncthreads();
    {
        const unsigned int* mw = (const unsigned int*)maskp;
        int lF = 0, lB = 0;
#pragma unroll
        for (int k = 0; k < 4; ++k) {
            unsigned w = mw[tid + (k << 10)];
            if (w == 0x3F800000u) lF = 1;
            else if (w > 1u) lB = 1;
        }
        if (lF) sF = 1;
        if (lB) sB = 1;
    }
    __syncthreads();
    const int mode = sF ? 2 : (sB ? 1 : 0);   // 0=int32, 1=bool bytes, 2=float32

    // ---------- B: per-thread mask read + block-wide inclusive scan (ranks) ----------
    int vis_me;
    {
        const int idx = (b << 10) + tid;
        if (mode == 1)      vis_me = ((const unsigned char*)maskp)[idx] != 0;
        else if (mode == 2) vis_me = ((const float*)maskp)[idx] != 0.f;
        else                vis_me = ((const int*)maskp)[idx] != 0;
    }
    visc_l[tid] = (unsigned char)vis_me;
    cs_[tid] = vis_me;
    __syncthreads();
    for (int off = 1; off < BLOCK; off <<= 1) {
        int x = (tid >= off) ? cs_[tid - off] : 0;
        __syncthreads();
        cs_[tid] += x;
        __syncthreads();
    }
    if (tid == 0) sInvn = 1.f / (float)cs_[Nn - 1];

    // ---------- C: softmax -> row-scaled fp8 q (global) + lse_l + qd_l ----------
#pragma unroll 1
    for (int r = 0; r < 64; ++r) {
        const int row = (wave << 6) + r;
        const float* rowp = logits + ((size_t)(b << 10) + row) * Cc;
        const float e0 = __expf(rowp[lane]);
        const float e1 = __expf(rowp[64 + lane]);
        const float e2 = __expf(rowp[128 + lane]);
        const float e3 = __expf(rowp[192 + lane]);
        const float e4 = __expf(rowp[256 + lane]);
        const float e5 = __expf(rowp[320 + lane]);
        const float e6 = __expf(rowp[384 + lane]);
        const float e7 = __expf(rowp[448 + lane]);
        float et = 0.f;
        if (tl) et = __expf(rowp[512 + lane]);
        float mx = fmaxf(fmaxf(fmaxf(e0, e1), fmaxf(e2, e3)),
                         fmaxf(fmaxf(e4, e5), fmaxf(e6, e7)));
        mx = wave_max(fmaxf(mx, et));
        const float s = wave_sum(e0 + e1 + e2 + e3 + e4 + e5 + e6 + e7 + et);
        const float fm = 416.f * RCP(mx);        // q_c = e_c*fm  (row scale fm*s on p)
        const unsigned w0 = enc4(e0 * fm, e1 * fm, e2 * fm, e3 * fm);
        const unsigned w1 = enc4(e4 * fm, e5 * fm, e6 * fm, e7 * fm);
        unsigned char* rowq = p8 + ((size_t)(b << 10) + row) * CPAD;
        *(unsigned long long*)(rowq + (lane << 3)) =
            (unsigned long long)w0 | ((unsigned long long)w1 << 32);
        if (tl) rowq[512 + lane] = (unsigned char)(enc4(et * fm, 0.f, 0.f, 0.f) & 0xffu);
        if (lane == 0) {
            lse_l[row] = __logf(s);
            qd_l[row] = dustp * fm * s;          // dust entry, same row scale
        }
    }
    __syncthreads();   // lse_l ready; q global stores drained

    // ---------- D: class NLL (exact fp32) ----------
    {
        float nll = 0.f;
        if (vis_me) {
            const int tgt = labels[(b << 10) + (cs_[tid] - 1)];
            nll = lse_l[tid] - logits[((size_t)(b << 10) + tid) * Cc + tgt];
        }
        nll = wave_sum(nll);
        if (lane == 0) redL[wave] = nll;
        __syncthreads();
        if (tid == 0) {
            float s = 0.f;
#pragma unroll
            for (int w = 0; w < NW; ++w) s += redL[w];
            sClass = s;
        }
    }
    // per-wave visibility bitmask (row r of this wave = bit r)
    const unsigned long long vmask = __ballot(visc_l[(wave << 6) + lane] != 0);
    __syncthreads();
    const float invn = sInvn;

    // ---------- E: 20 Sinkhorn iterations (colsum fan-in entirely in LDS) ----------
    for (int t = 0; t < ITERS; ++t) {
        if (tid < CP1) {
            float ev = 1.f;                      // iter 0: v=0 -> ev=1
            if (t) {
                float s = 0.f;
#pragma unroll
                for (int w = 0; w < NW; ++w) s += partl[w][tid];
                ev = RCP(559.f * s);
            }
            evl[tid] = ev;
        }
        __syncthreads();
        const float evr0 = evl[lane],        evr1 = evl[64 + lane];
        const float evr2 = evl[128 + lane],  evr3 = evl[192 + lane];
        const float evr4 = evl[256 + lane],  evr5 = evl[320 + lane];
        const float evr6 = evl[384 + lane],  evr7 = evl[448 + lane];
        const float evt = tl ? evl[512 + lane] : 0.f;
        const float evd = evl[558];
        float pc0 = 0.f, pc1 = 0.f, pc2 = 0.f, pc3 = 0.f;
        float pc4 = 0.f, pc5 = 0.f, pc6 = 0.f, pc7 = 0.f;
        float pct = 0.f, pcd = 0.f;
#pragma unroll 2
        for (int r = 0; r < 64; ++r) {
            const int row = (wave << 6) + r;
            if ((vmask >> r) & 1ull) {           // wave-uniform branch
                const unsigned char* rowq = p8 + ((size_t)(b << 10) + row) * CPAD;
                const unsigned long long wq =
                    *(const unsigned long long*)(rowq + (lane << 3));
                float f0, f1, f2, f3, f4, f5, f6, f7;
                dec4((unsigned)wq, f0, f1, f2, f3);
                dec4((unsigned)(wq >> 32), f4, f5, f6, f7);
                float xt = 0.f;
                if (tl) xt = dec1(rowq[512 + lane]);
                const float qdr = qd_l[row];
                float s = f0 * evr0 + f1 * evr1 + f2 * evr2 + f3 * evr3
                        + f4 * evr4 + f5 * evr5 + f6 * evr6 + f7 * evr7 + xt * evt;
                s = wave_sum(s) + qdr * evd;
                const float euv = invn * RCP(s);
                if (lane == 0) eu_l[row] = euv;
                pc0 += f0 * euv; pc1 += f1 * euv; pc2 += f2 * euv; pc3 += f3 * euv;
                pc4 += f4 * euv; pc5 += f5 * euv; pc6 += f6 * euv; pc7 += f7 * euv;
                pct += xt * euv; pcd += qdr * euv;
            } else if (lane == 0) {
                eu_l[row] = 0.f;
            }
        }
        // strided ownership: consecutive lanes -> consecutive banks, conflict-free
        partl[wave][lane] = pc0;        partl[wave][64 + lane] = pc1;
        partl[wave][128 + lane] = pc2;  partl[wave][192 + lane] = pc3;
        partl[wave][256 + lane] = pc4;  partl[wave][320 + lane] = pc5;
        partl[wave][384 + lane] = pc6;  partl[wave][448 + lane] = pc7;
        if (tl) partl[wave][512 + lane] = pct;
        if (lane == 0) partl[wave][558] = pcd;
        __syncthreads();
    }

    // ---------- F: final ev + entropy of plan (excludes dust col) + combine ----------
    if (tid < CP1) {
        float s = 0.f;
#pragma unroll
        for (int w = 0; w < NW; ++w) s += partl[w][tid];
        evl[tid] = RCP(559.f * s);
    }
    __syncthreads();
    {
        const float evr0 = evl[lane],        evr1 = evl[64 + lane];
        const float evr2 = evl[128 + lane],  evr3 = evl[192 + lane];
        const float evr4 = evl[256 + lane],  evr5 = evl[320 + lane];
        const float evr6 = evl[384 + lane],  evr7 = evl[448 + lane];
        const float evt = tl ? evl[512 + lane] : 0.f;
        float acc = 0.f;
#pragma unroll 1
        for (int r = 0; r < 64; ++r) {
            if (!((vmask >> r) & 1ull)) continue;   // invisible row: contributes 0
            const int row = (wave << 6) + r;
            const float euv = eu_l[row];
            const unsigned char* rowq = p8 + ((size_t)(b << 10) + row) * CPAD;
            const unsigned long long wq = *(const unsigned long long*)(rowq + (lane << 3));
            float f0, f1, f2, f3, f4, f5, f6, f7;
            dec4((unsigned)wq, f0, f1, f2, f3);
            dec4((unsigned)(wq >> 32), f4, f5, f6, f7);
            float xt = 0.f;
            if (tl) xt = dec1(rowq[512 + lane]);
            float P;
            P = f0 * euv * evr0; acc -= P * __logf(P + 1e-8f);
            P = f1 * euv * evr1; acc -= P * __logf(P + 1e-8f);
            P = f2 * euv * evr2; acc -= P * __logf(P + 1e-8f);
            P = f3 * euv * evr3; acc -= P * __logf(P + 1e-8f);
            P = f4 * euv * evr4; acc -= P * __logf(P + 1e-8f);
            P = f5 * euv * evr5; acc -= P * __logf(P + 1e-8f);
            P = f6 * euv * evr6; acc -= P * __logf(P + 1e-8f);
            P = f7 * euv * evr7; acc -= P * __logf(P + 1e-8f);
            P = xt * euv * evt;  acc -= P * __logf(P + 1e-8f);
        }
        acc = wave_sum(acc);
        if (lane == 0) redL[wave] = acc;
    }
    __syncthreads();
    if (tid == 0) {
        float ent = 0.f;
#pragma unroll
        for (int w = 0; w < NW; ++w) ent += redL[w];
        contrib[b] = (sClass + 0.5f * ent) * sInvn;
    }
}

// ---- K4: mean over batches ----
__global__ void k4_out(const float* __restrict__ contrib, float* __restrict__ out) {
    float v = contrib[threadIdx.x];   // 64 threads = 1 wave
    v = wave_sum(v);
    if (threadIdx.x == 0) out[0] = v * (1.f / 64.f);
}

extern "C" void kernel_launch(void* const* d_in, const int* in_sizes, int n_in,
                              void* d_out, int out_size, void* d_ws, size_t ws_size,
                              hipStream_t stream) {
    const float* logits = (const float*)d_in[0];
    const float* dustbin = (const float*)d_in[1];
    const int* labels = (const int*)d_in[2];
    const void* mask = d_in[3];
    float* out = (float*)d_out;

    char* ws = (char*)d_ws;
    size_t off = 0;
    unsigned char* p8 = (unsigned char*)(ws + off); off += (size_t)Bb * Nn * CPAD;  // 36.7 MB
    float* contrib = (float*)(ws + off);            off += Bb * 4;

    k_fused<<<Bb, BLOCK, 0, stream>>>(logits, dustbin, labels, mask, p8, contrib);
    k4_out<<<1, 64, 0, stream>>>(contrib, out);
    (void)in_sizes; (void)n_in; (void)out_size; (void)ws_size;
}

// Round 9
// 618.806 us; speedup vs baseline: 1.4420x; 1.4420x over previous
//
#include <hip/hip_runtime.h>

#define Bb 64
#define Nn 1024
#define Cc 558
#define CP1 559
#define CPAD 560
#define ITERS 20
#define NW 16                  /* waves per block in k_iter */
#define BLOCK 1024

#if __has_builtin(__builtin_amdgcn_rcpf)
#define RCP(x) __builtin_amdgcn_rcpf(x)
#else
#define RCP(x) (1.0f / (x))
#endif

// ---------------- wave reductions on the VALU pipe (DPP), result uniform ----------------
#if __has_builtin(__builtin_amdgcn_update_dpp) && __has_builtin(__builtin_amdgcn_readlane)
template <int CTRL>
__device__ __forceinline__ float dpp_mv(float x) {
    return __int_as_float(
        __builtin_amdgcn_update_dpp(0, __float_as_int(x), CTRL, 0xf, 0xf, true));
}
__device__ __forceinline__ float wave_sum(float x) {
    x += dpp_mv<0x111>(x);   // row_shr:1
    x += dpp_mv<0x112>(x);   // row_shr:2
    x += dpp_mv<0x114>(x);   // row_shr:4
    x += dpp_mv<0x118>(x);   // row_shr:8
    x += dpp_mv<0x142>(x);   // row_bcast:15
    x += dpp_mv<0x143>(x);   // row_bcast:31  -> lane 63 holds the total
    return __int_as_float(__builtin_amdgcn_readlane(__float_as_int(x), 63));
}
__device__ __forceinline__ float wave_max(float x) {   // operands are > 0
    x = fmaxf(x, dpp_mv<0x111>(x));
    x = fmaxf(x, dpp_mv<0x112>(x));
    x = fmaxf(x, dpp_mv<0x114>(x));
    x = fmaxf(x, dpp_mv<0x118>(x));
    x = fmaxf(x, dpp_mv<0x142>(x));
    x = fmaxf(x, dpp_mv<0x143>(x));
    return __int_as_float(__builtin_amdgcn_readlane(__float_as_int(x), 63));
}
#else
__device__ __forceinline__ float wave_sum(float v) {
#pragma unroll
    for (int off = 32; off > 0; off >>= 1) v += __shfl_xor(v, off, 64);
    return v;
}
__device__ __forceinline__ float wave_max(float v) {
#pragma unroll
    for (int off = 32; off > 0; off >>= 1) v = fmaxf(v, __shfl_xor(v, off, 64));
    return v;
}
#endif

// ---------------- fp8 e4m3 helpers (values >= 0, normal range; HW-validated R5-R7) ----
#if __has_builtin(__builtin_amdgcn_cvt_pk_fp8_f32) && __has_builtin(__builtin_amdgcn_cvt_pk_f32_fp8)
#define HW_FP8 1
typedef float v2f __attribute__((ext_vector_type(2)));
#endif

__device__ __forceinline__ unsigned enc1_sw(float v) {
    if (!(v > 0.f)) return 0u;
    unsigned u = __float_as_uint(v);
    unsigned t = u + 0x7FFFFu + ((u >> 20) & 1u);   // RNE to 3 mantissa bits
    int e = (int)(t >> 23) - 120;
    if (e < 1) return 0u;
    if (e > 15) return 0x7Eu;
    return ((unsigned)e << 3) | ((t >> 20) & 7u);
}
__device__ __forceinline__ float dec1_sw(unsigned b8) {
    return b8 ? __uint_as_float((((b8 >> 3) + 120u) << 23) | ((b8 & 7u) << 20)) : 0.f;
}
__device__ __forceinline__ unsigned enc4(float f0, float f1, float f2, float f3) {
#ifdef HW_FP8
    int w = 0;
    w = __builtin_amdgcn_cvt_pk_fp8_f32(f0, f1, w, false);
    w = __builtin_amdgcn_cvt_pk_fp8_f32(f2, f3, w, true);
    return (unsigned)w;
#else
    return enc1_sw(f0) | (enc1_sw(f1) << 8) | (enc1_sw(f2) << 16) | (enc1_sw(f3) << 24);
#endif
}
__device__ __forceinline__ void dec4(unsigned w, float& f0, float& f1, float& f2, float& f3) {
#ifdef HW_FP8
    v2f a = __builtin_amdgcn_cvt_pk_f32_fp8((int)w, false);
    v2f b = __builtin_amdgcn_cvt_pk_f32_fp8((int)w, true);
    f0 = a[0]; f1 = a[1]; f2 = b[0]; f3 = b[1];
#else
    f0 = dec1_sw(w & 0xffu); f1 = dec1_sw((w >> 8) & 0xffu);
    f2 = dec1_sw((w >> 16) & 0xffu); f3 = dec1_sw(w >> 24);
#endif
}
__device__ __forceinline__ float dec1(unsigned b8) {
#ifdef HW_FP8
    v2f a = __builtin_amdgcn_cvt_pk_f32_fp8((int)(b8 & 0xffu), false);
    return a[0];
#else
    return dec1_sw(b8 & 0xffu);
#endif
}

// ---- K0 (full chip): per-row softmax -> row-scaled fp8 q + lse + scaled dust qd ----
// Layout: byte row*560 + 8*l + k holds col 64k+l (k=0..7); byte row*560+512+l holds col 512+l.
__global__ __launch_bounds__(256) void k0_softmax(const float* __restrict__ logits,
        const float* __restrict__ dustbin, unsigned char* __restrict__ p8,
        float* __restrict__ qd, float* __restrict__ lse) {
    const int wave = threadIdx.x >> 6, lane = threadIdx.x & 63;
    const int r = (blockIdx.x << 2) + wave;
    const float* rowp = logits + (size_t)r * Cc;
    const bool tl = lane < 46;
    const float e0 = __expf(rowp[lane]);
    const float e1 = __expf(rowp[64 + lane]);
    const float e2 = __expf(rowp[128 + lane]);
    const float e3 = __expf(rowp[192 + lane]);
    const float e4 = __expf(rowp[256 + lane]);
    const float e5 = __expf(rowp[320 + lane]);
    const float e6 = __expf(rowp[384 + lane]);
    const float e7 = __expf(rowp[448 + lane]);
    float et = 0.f;
    if (tl) et = __expf(rowp[512 + lane]);
    float mx = fmaxf(fmaxf(fmaxf(e0, e1), fmaxf(e2, e3)),
                     fmaxf(fmaxf(e4, e5), fmaxf(e6, e7)));
    mx = wave_max(fmaxf(mx, et));
    const float s = wave_sum(e0 + e1 + e2 + e3 + e4 + e5 + e6 + e7 + et);
    const float fm = 416.f * RCP(mx);            // q_c = e_c*fm  (row scale = fm*s on p)
    const unsigned w0 = enc4(e0 * fm, e1 * fm, e2 * fm, e3 * fm);
    const unsigned w1 = enc4(e4 * fm, e5 * fm, e6 * fm, e7 * fm);
    unsigned char* rowq = p8 + (size_t)r * CPAD;
    *(unsigned long long*)(rowq + (lane << 3)) =
        (unsigned long long)w0 | ((unsigned long long)w1 << 32);
    if (tl) rowq[512 + lane] = (unsigned char)(enc4(et * fm, 0.f, 0.f, 0.f) & 0xffu);
    if (lane == 0) {
        qd[r] = __expf(dustbin[0]) * fm * s;     // dust entry, same row scale
        lse[r] = __logf(s);
    }
}

// ---- K1: mask-format detect + per-batch mask scan + class loss (R6-proven) ----
__global__ __launch_bounds__(256) void k1_batch(const float* __restrict__ logits,
        const int* __restrict__ labels, const void* __restrict__ maskp,
        const float* __restrict__ lse, float* __restrict__ class_part,
        float* __restrict__ inv_nvis, unsigned char* __restrict__ visc) {
    const int b = blockIdx.x, tid = threadIdx.x;
    __shared__ int sF, sB;
    __shared__ int cs_[256];
    __shared__ float red[256];
    if (tid == 0) { sF = 0; sB = 0; }
    __syncthreads();
    {
        const unsigned int* mw = (const unsigned int*)maskp;
        int lF = 0, lB = 0;
        for (int i = tid; i < (Bb * Nn) / 4; i += 256) {
            unsigned w = mw[i];
            if (w == 0x3F800000u) lF = 1;
            else if (w > 1u) lB = 1;
        }
        if (lF) sF = 1;
        if (lB) sB = 1;
    }
    __syncthreads();
    const int mode = sF ? 2 : (sB ? 1 : 0);   // 0=int32, 1=bool bytes, 2=float32
    int v[4]; int local = 0;
#pragma unroll
    for (int j = 0; j < 4; ++j) {
        const int n = tid * 4 + j;
        const int idx = b * Nn + n;
        int m;
        if (mode == 1)      m = ((const unsigned char*)maskp)[idx] != 0;
        else if (mode == 2) m = ((const float*)maskp)[idx] != 0.f;
        else                m = ((const int*)maskp)[idx] != 0;
        v[j] = m; local += m;
    }
    cs_[tid] = local;
    __syncthreads();
    for (int off = 1; off < 256; off <<= 1) {   // inclusive scan
        int x = 0;
        if (tid >= off) x = cs_[tid - off];
        __syncthreads();
        cs_[tid] += x;
        __syncthreads();
    }
    const int nvis = cs_[255];
    int run = cs_[tid] - local;                  // exclusive prefix
    float nllsum = 0.f;
#pragma unroll
    for (int j = 0; j < 4; ++j) {
        const int n = tid * 4 + j;
        run += v[j];
        visc[b * Nn + n] = (unsigned char)v[j];
        if (v[j]) {
            const int tgt = labels[b * Nn + (run - 1)];
            nllsum += lse[b * Nn + n] - logits[((size_t)(b * Nn + n)) * Cc + tgt];
        }
    }
    red[tid] = nllsum;
    __syncthreads();
    for (int off = 128; off > 0; off >>= 1) {
        if (tid < off) red[tid] += red[tid + off];
        __syncthreads();
    }
    if (tid == 0) {
        class_part[b] = red[0] / (float)nvis;
        inv_nvis[b] = 1.f / (float)nvis;
    }
}

// ---- K_ITER: one block per batch; 20 Sinkhorn iterations + entropy. Branchless rows,
//      8-row load groups, DPP reductions (VALU pipe), LDS colsum fan-in. ----
__global__ __launch_bounds__(BLOCK) void k_iter(
        const unsigned char* __restrict__ p8, const float* __restrict__ qd,
        const unsigned char* __restrict__ visc, const float* __restrict__ inv_nvis,
        float* __restrict__ assign_part) {
    __shared__ float partl[NW][CPAD];        // 35.8 KB, strided ownership (conflict-free)
    __shared__ float evl[CPAD];
    __shared__ float qd_l[Nn];
    __shared__ float vf_l[Nn];
    __shared__ float eu_l[Nn];
    __shared__ float redE[NW];
    const int b = blockIdx.x, tid = threadIdx.x;
    const int wave = tid >> 6, lane = tid & 63;
    const bool tl = lane < 46;
    const float invn = inv_nvis[b];
    const unsigned char* qb = p8 + ((size_t)b << 10) * CPAD;

    qd_l[tid] = qd[(b << 10) + tid];
    vf_l[tid] = visc[(b << 10) + tid] ? invn : 0.f;
    __syncthreads();

    // ---------- 20 Sinkhorn iterations ----------
    for (int t = 0; t < ITERS; ++t) {
        if (tid < CP1) {
            float ev = 1.f;                      // iter 0: v=0 -> ev=1
            if (t) {
                float s = 0.f;
#pragma unroll
                for (int w = 0; w < NW; ++w) s += partl[w][tid];
                ev = RCP(559.f * s);
            }
            evl[tid] = ev;
        }
        __syncthreads();
        const float evr0 = evl[lane],        evr1 = evl[64 + lane];
        const float evr2 = evl[128 + lane],  evr3 = evl[192 + lane];
        const float evr4 = evl[256 + lane],  evr5 = evl[320 + lane];
        const float evr6 = evl[384 + lane],  evr7 = evl[448 + lane];
        const float evt = tl ? evl[512 + lane] : 0.f;
        const float evd = evl[558];
        float pc0 = 0.f, pc1 = 0.f, pc2 = 0.f, pc3 = 0.f;
        float pc4 = 0.f, pc5 = 0.f, pc6 = 0.f, pc7 = 0.f;
        float pct = 0.f, pcd = 0.f;
        for (int g = 0; g < 64; g += 8) {
            unsigned long long wq[8];
            unsigned tb[8];
#pragma unroll
            for (int j = 0; j < 8; ++j) {        // 16 loads in flight
                const unsigned char* rowq = qb + (size_t)((wave << 6) + g + j) * CPAD;
                wq[j] = *(const unsigned long long*)(rowq + (lane << 3));
                tb[j] = rowq[512 + lane];        // lanes>=46 read pad; masked by evt=0
            }
#pragma unroll
            for (int j = 0; j < 8; ++j) {
                const int row = (wave << 6) + g + j;
                float f0, f1, f2, f3, f4, f5, f6, f7;
                dec4((unsigned)wq[j], f0, f1, f2, f3);
                dec4((unsigned)(wq[j] >> 32), f4, f5, f6, f7);
                const float xt = dec1(tb[j]);
                float s = f0 * evr0 + f1 * evr1 + f2 * evr2 + f3 * evr3
                        + f4 * evr4 + f5 * evr5 + f6 * evr6 + f7 * evr7 + xt * evt;
                s = wave_sum(s);
                const float qdr = qd_l[row];
                const float euv = vf_l[row] * RCP(s + qdr * evd);   // 0 if invisible
                if (lane == 0) eu_l[row] = euv;
                pc0 += f0 * euv; pc1 += f1 * euv; pc2 += f2 * euv; pc3 += f3 * euv;
                pc4 += f4 * euv; pc5 += f5 * euv; pc6 += f6 * euv; pc7 += f7 * euv;
                pct += xt * euv; pcd += qdr * euv;
            }
        }
        partl[wave][lane] = pc0;        partl[wave][64 + lane] = pc1;
        partl[wave][128 + lane] = pc2;  partl[wave][192 + lane] = pc3;
        partl[wave][256 + lane] = pc4;  partl[wave][320 + lane] = pc5;
        partl[wave][384 + lane] = pc6;  partl[wave][448 + lane] = pc7;
        if (tl) partl[wave][512 + lane] = pct;
        if (lane == 0) partl[wave][558] = pcd;
        __syncthreads();
    }

    // ---------- final ev + entropy (branchless; invisible rows give P=0 -> 0) ----------
    if (tid < CP1) {
        float s = 0.f;
#pragma unroll
        for (int w = 0; w < NW; ++w) s += partl[w][tid];
        evl[tid] = RCP(559.f * s);
    }
    __syncthreads();
    {
        const float evr0 = evl[lane],        evr1 = evl[64 + lane];
        const float evr2 = evl[128 + lane],  evr3 = evl[192 + lane];
        const float evr4 = evl[256 + lane],  evr5 = evl[320 + lane];
        const float evr6 = evl[384 + lane],  evr7 = evl[448 + lane];
        const float evt = tl ? evl[512 + lane] : 0.f;
        float acc = 0.f;
        for (int g = 0; g < 64; g += 4) {
            unsigned long long wq[4];
            unsigned tb[4];
#pragma unroll
            for (int j = 0; j < 4; ++j) {
                const unsigned char* rowq = qb + (size_t)((wave << 6) + g + j) * CPAD;
                wq[j] = *(const unsigned long long*)(rowq + (lane << 3));
                tb[j] = rowq[512 + lane];
            }
#pragma unroll
            for (int j = 0; j < 4; ++j) {
                const int row = (wave << 6) + g + j;
                const float euv = eu_l[row];
                float f0, f1, f2, f3, f4, f5, f6, f7;
                dec4((unsigned)wq[j], f0, f1, f2, f3);
                dec4((unsigned)(wq[j] >> 32), f4, f5, f6, f7);
                const float xt = dec1(tb[j]);
                float P;
                P = f0 * euv * evr0; acc -= P * __logf(P + 1e-8f);
                P = f1 * euv * evr1; acc -= P * __logf(P + 1e-8f);
                P = f2 * euv * evr2; acc -= P * __logf(P + 1e-8f);
                P = f3 * euv * evr3; acc -= P * __logf(P + 1e-8f);
                P = f4 * euv * evr4; acc -= P * __logf(P + 1e-8f);
                P = f5 * euv * evr5; acc -= P * __logf(P + 1e-8f);
                P = f6 * euv * evr6; acc -= P * __logf(P + 1e-8f);
                P = f7 * euv * evr7; acc -= P * __logf(P + 1e-8f);
                P = xt * euv * evt;  acc -= P * __logf(P + 1e-8f);
            }
        }
        acc = wave_sum(acc);
        if (lane == 0) redE[wave] = acc;
    }
    __syncthreads();
    if (tid == 0) {
        float ent = 0.f;
#pragma unroll
        for (int w = 0; w < NW; ++w) ent += redE[w];
        assign_part[b] = ent * invn;
    }
}

// ---- K4: combine ----
__global__ void k4_out(const float* __restrict__ class_part,
                       const float* __restrict__ assign_part, float* __restrict__ out) {
    const int b = threadIdx.x;   // 64 threads = 1 wave
    float v = class_part[b] + 0.5f * assign_part[b];
    v = wave_sum(v);
    if (b == 0) out[0] = v * (1.f / 64.f);
}

extern "C" void kernel_launch(void* const* d_in, const int* in_sizes, int n_in,
                              void* d_out, int out_size, void* d_ws, size_t ws_size,
                              hipStream_t stream) {
    const float* logits = (const float*)d_in[0];
    const float* dustbin = (const float*)d_in[1];
    const int* labels = (const int*)d_in[2];
    const void* mask = d_in[3];
    float* out = (float*)d_out;

    char* ws = (char*)d_ws;
    size_t off = 0;
    unsigned char* p8 = (unsigned char*)(ws + off); off += (size_t)Bb * Nn * CPAD;  // 36.7 MB
    float* qd = (float*)(ws + off);            off += (size_t)Bb * Nn * 4;
    float* lse = (float*)(ws + off);           off += (size_t)Bb * Nn * 4;
    unsigned char* visc = (unsigned char*)(ws + off); off += (size_t)Bb * Nn;
    float* inv_nvis = (float*)(ws + off);      off += Bb * 4;
    float* class_part = (float*)(ws + off);    off += Bb * 4;
    float* assign_part = (float*)(ws + off);   off += Bb * 4;

    k0_softmax<<<(Bb * Nn) / 4, 256, 0, stream>>>(logits, dustbin, p8, qd, lse);
    k1_batch<<<Bb, 256, 0, stream>>>(logits, labels, mask, lse,
                                     class_part, inv_nvis, visc);
    k_iter<<<Bb, BLOCK, 0, stream>>>(p8, qd, visc, inv_nvis, assign_part);
    k4_out<<<1, 64, 0, stream>>>(class_part, assign_part, out);
    (void)in_sizes; (void)n_in; (void)out_size; (void)ws_size;
}